// Round 2
// baseline (106.993 us; speedup 1.0000x reference)
//
#include <hip/hip_runtime.h>
#include <hip/hip_bf16.h>
#include <math.h>

#define KC 64
#define DD 128
#define NN 4096

// ws layout (float offsets)
#define OFF_FHAT   0u        // 4096*128 = 524288
#define OFF_MUHAT  524288u   // 8192
#define OFF_SUMS   532480u   // 8192
#define OFF_CNTS   540672u   // 64
#define OFF_KAP    540736u   // 64
#define OFF_LOGC   540800u   // 64
#define OFF_AA     540864u   // 64
#define OFF_P      540928u   // 4096
#define WS_TOTAL   545024u

#define LOG2PI 1.8378770664093453f
#define LN2    0.6931471805599453f
#define GAMMALN64 201.00931639928152f

__device__ __forceinline__ float wave_sum(float v) {
  #pragma unroll
  for (int off = 32; off > 0; off >>= 1) v += __shfl_xor(v, off, 64);
  return v;
}

// K1: normalize features (+ atomic class sums/counts); block 256: mus + kappa/logC/A
__global__ __launch_bounds__(256) void k_prep(const float* __restrict__ feat,
                                              const float* __restrict__ musp,
                                              const float* __restrict__ rho,
                                              const int* __restrict__ labels,
                                              float* __restrict__ ws) {
  float* fhat  = ws + OFF_FHAT;
  float* muhat = ws + OFF_MUHAT;
  float* sums  = ws + OFF_SUMS;
  float* cnts  = ws + OFF_CNTS;
  float* kap   = ws + OFF_KAP;
  float* logC  = ws + OFF_LOGC;
  float* Aa    = ws + OFF_AA;
  int tid = threadIdx.x;
  int wave = tid >> 6, lane = tid & 63;

  if (blockIdx.x == 256) {
    if (tid < KC) {
      float x = rho[tid];
      // softplus, numerically stable: max(x,0)+log1p(exp(-|x|))
      float sp = fmaxf(x, 0.f) + log1pf(expf(-fabsf(x)));
      float kp = fmaxf(sp, 1e-6f);
      kap[tid] = kp;
      float logI;
      if (kp < 1e-3f)
        logI = 63.f * logf(kp * 0.5f + 1e-12f) - GAMMALN64;
      else
        logI = kp - 0.5f * logf(6.283185307179586f * kp + 1e-12f);
      logC[tid] = -63.f * logf(kp + 1e-12f) - 64.f * LOG2PI - logI;
      float kc = fmaxf(kp, 1e-8f);
      Aa[tid] = (kc > 50.f) ? (1.f - 127.f / (2.f * kc)) : (kc * (1.f / 128.f));
    }
    for (int r = wave; r < KC; r += 4) {
      float x0 = musp[r * DD + lane];
      float x1 = musp[r * DD + 64 + lane];
      float ss = wave_sum(x0 * x0 + x1 * x1);
      float inv = 1.f / fmaxf(sqrtf(ss), 1e-12f);
      muhat[r * DD + lane]      = x0 * inv;
      muhat[r * DD + 64 + lane] = x1 * inv;
    }
  } else {
    int gw = blockIdx.x * 4 + wave;  // 0..1023
    for (int n = gw; n < NN; n += 1024) {
      float x0 = feat[n * DD + lane];
      float x1 = feat[n * DD + 64 + lane];
      float ss = wave_sum(x0 * x0 + x1 * x1);
      float inv = 1.f / fmaxf(sqrtf(ss), 1e-12f);
      x0 *= inv; x1 *= inv;
      fhat[n * DD + lane]      = x0;
      fhat[n * DD + 64 + lane] = x1;
      int c = labels[n];
      atomicAdd(&sums[c * DD + lane], x0);
      atomicAdd(&sums[c * DD + 64 + lane], x1);
      if (lane == 0) atomicAdd(&cnts[c], 1.f);
    }
  }
}

// K2: per row n: L[n,j] = logC[j] + kap[j]*dot(fhat[n], mu[j]); accumulate
// P[c,j] += L[n,c] + ln2 - logaddexp(L[n,c], L[n,j])
__global__ __launch_bounds__(256) void k_main(const float* __restrict__ ws,
                                              const int* __restrict__ labels,
                                              float* __restrict__ P) {
  __shared__ float mu_t[128 * 65];
  __shared__ float kap_s[KC], logC_s[KC];
  const float* fhat  = ws + OFF_FHAT;
  const float* muhat = ws + OFF_MUHAT;
  const float* kap   = ws + OFF_KAP;
  const float* logC  = ws + OFF_LOGC;
  int tid = threadIdx.x;
  for (int idx = tid; idx < 8192; idx += 256) {
    int r = idx >> 7, d = idx & 127;
    mu_t[d * 65 + r] = muhat[idx];   // transposed, pad 65 -> conflict-free
  }
  if (tid < KC) { kap_s[tid] = kap[tid]; logC_s[tid] = logC[tid]; }
  __syncthreads();

  int wave = tid >> 6, lane = tid & 63;
  int gw = blockIdx.x * 4 + wave;   // 1024 waves
  for (int n = gw; n < NN; n += 1024) {
    float f0 = fhat[n * DD + lane];
    float f1 = fhat[n * DD + 64 + lane];
    float a0 = 0.f, a1 = 0.f;
    #pragma unroll
    for (int d = 0; d < 64; d += 2) {
      a0 += __shfl(f0, d, 64)     * mu_t[d * 65 + lane];
      a1 += __shfl(f0, d + 1, 64) * mu_t[(d + 1) * 65 + lane];
    }
    #pragma unroll
    for (int d = 0; d < 64; d += 2) {
      a0 += __shfl(f1, d, 64)     * mu_t[(d + 64) * 65 + lane];
      a1 += __shfl(f1, d + 1, 64) * mu_t[(d + 65) * 65 + lane];
    }
    float Lj = logC_s[lane] + kap_s[lane] * (a0 + a1);
    int c = labels[n];
    float a = __shfl(Lj, c, 64);
    float m = fmaxf(a, Lj);
    float lae = m + log1pf(expf(-fabsf(a - Lj)));
    float val = a + LN2 - lae;
    atomicAdd(&P[c * KC + lane], val);
  }
}

// K3: block i (1 wave): rank hinge row i + js row i; atomicAdd into out
__global__ __launch_bounds__(64) void k_final(const float* __restrict__ ws,
                                              float* __restrict__ out) {
  __shared__ float mu_t[128 * 65];
  const float* muhat = ws + OFF_MUHAT;
  const float* sums  = ws + OFF_SUMS;
  const float* cnts  = ws + OFF_CNTS;
  const float* kap   = ws + OFF_KAP;
  const float* logC  = ws + OFF_LOGC;
  const float* Aa    = ws + OFF_AA;
  const float* P     = ws + OFF_P;
  int j = threadIdx.x;   // 0..63
  int i = blockIdx.x;    // 0..63
  for (int idx = j; idx < 8192; idx += 64) {
    int r = idx >> 7, d = idx & 127;
    mu_t[d * 65 + r] = muhat[idx];
  }
  __syncthreads();

  float cnt_i = cnts[i];
  float cs_i  = fmaxf(cnt_i, 1.f);
  // means[i] in regs (lane j holds elems j and j+64), with zero-count fallback
  float m0, m1;
  if (cnt_i == 0.f) {
    m0 = mu_t[j * 65 + i];          // muhat[i][j]  (mu_t[d][r] = muhat[r][d])
    m1 = mu_t[(j + 64) * 65 + i];
  } else {
    m0 = sums[i * DD + j] / cs_i;
    m1 = sums[i * DD + 64 + j] / cs_i;
  }
  float dot_j = 0.f;
  #pragma unroll
  for (int d = 0; d < 64; ++d) dot_j += __shfl(m0, d, 64) * mu_t[d * 65 + j];
  #pragma unroll
  for (int d = 0; d < 64; ++d) dot_j += __shfl(m1, d, 64) * mu_t[(d + 64) * 65 + j];

  float diag  = __shfl(dot_j, i, 64);
  float kap_i = kap[i], kap_j = kap[j];
  float E_si  = kap_i * diag;
  float w     = fabsf((float)(i - j));
  float diff  = E_si - kap_j * dot_j;
  float hinge = (i == j) ? 0.f : fmaxf(0.f, 0.5f * w - diff);
  float rank_part = wave_sum(hinge) / cs_i;

  float cnt_j = cnts[j];
  float cs_j  = fmaxf(cnt_j, 1.f);
  float js_v;
  if (cnt_i == 0.f || cnt_j == 0.f) {
    float md = 0.f;
    for (int d = 0; d < 128; ++d) md += mu_t[d * 65 + i] * mu_t[d * 65 + j];
    float kl_ij = logC[i] - logC[j] + Aa[i] * (kap_i - kap_j * md);
    float kl_ji = logC[j] - logC[i] + Aa[j] * (kap_j - kap_i * md);
    js_v = 0.5f * (kl_ij + kl_ji);
  } else {
    js_v = 0.5f * (P[i * KC + j] / cs_i + P[j * KC + i] / cs_j);
  }
  float js_part = wave_sum(w * js_v);
  if (j == 0)
    atomicAdd(out, rank_part * (1.f / 4096.f) + js_part * (1.f / 87360.f));
}

extern "C" void kernel_launch(void* const* d_in, const int* in_sizes, int n_in,
                              void* d_out, int out_size, void* d_ws, size_t ws_size,
                              hipStream_t stream) {
  const float* feat = (const float*)d_in[0];
  const float* musp = (const float*)d_in[1];
  const float* rho  = (const float*)d_in[2];
  const int*   lab  = (const int*)d_in[3];
  float* ws  = (float*)d_ws;
  float* out = (float*)d_out;

  // zero sums/cnts/kap/logC/A/P region and the output accumulator
  hipMemsetAsync(ws + OFF_SUMS, 0, (WS_TOTAL - OFF_SUMS) * sizeof(float), stream);
  hipMemsetAsync(out, 0, sizeof(float), stream);

  k_prep<<<257, 256, 0, stream>>>(feat, musp, rho, lab, ws);
  k_main<<<256, 256, 0, stream>>>(ws, lab, ws + OFF_P);
  k_final<<<64, 64, 0, stream>>>(ws, out);
}

// Round 4
// 77.586 us; speedup vs baseline: 1.3790x; 1.3790x over previous
//
#include <hip/hip_runtime.h>
#include <hip/hip_bf16.h>
#include <math.h>

#define KC 64
#define DD 128
#define NN 4096

// ws float offsets
#define OFF_MUHAT 0u       // 8192
#define OFF_KAP   8192u    // 64
#define OFF_LOGC  8256u    // 64
#define OFF_AA    8320u    // 64
#define OFF_SUMSP 8384u    // 256*128 = 32768  (per-block class-sum partials)
#define OFF_CNTP  41152u   // 256               (per-block count partials)
#define OFF_PP    41408u   // 256*64 = 16384    (per-block P-row partials)

#define LOG2PI 1.8378770664093453f
#define LN2    0.6931471805599453f
#define GAMMALN64 201.00931639928152f

__device__ __forceinline__ float wave_sum(float v) {
  #pragma unroll
  for (int off = 32; off > 0; off >>= 1) v += __shfl_xor(v, off, 64);
  return v;
}

// Kernel A: block b = (sub, c); sub = b>>6 owns rows [sub*1024, sub*1024+1024),
// c = b&63 owns class c. Finds its rows, normalizes them in-reg, computes
// L[n,:] via LDS dot, accumulates P-row-c / class-sum / count with NO atomics.
__global__ __launch_bounds__(512) void k_classes(const float* __restrict__ feat,
                                                 const float* __restrict__ musp,
                                                 const float* __restrict__ rho,
                                                 const int* __restrict__ lab,
                                                 float* __restrict__ ws) {
  __shared__ __align__(16) float mu_t[DD][65];   // mu_t[d][r] = muhat[r][d]
  __shared__ float kap_s[KC], logC_s[KC];
  __shared__ __align__(16) float f_s[8][132];
  __shared__ float redS[8][DD];
  __shared__ float redP[8][KC];
  __shared__ int wl[1024];
  __shared__ int wl_cnt;

  const int tid = threadIdx.x;
  const int w = tid >> 6, l = tid & 63;
  const int b = blockIdx.x, c = b & 63, sub = b >> 6;
  if (tid == 0) wl_cnt = 0;

  // stage normalized mus (transposed) — redundant per block, trivial
  #pragma unroll
  for (int rr = 0; rr < 8; ++rr) {
    int r = w * 8 + rr;
    float x0 = musp[r * DD + l];
    float x1 = musp[r * DD + 64 + l];
    float ss = wave_sum(x0 * x0 + x1 * x1);
    float inv = 1.f / fmaxf(sqrtf(ss), 1e-12f);
    mu_t[l][r]      = x0 * inv;
    mu_t[l + 64][r] = x1 * inv;
  }
  if (tid < KC) {
    float x = rho[tid];
    float sp = fmaxf(x, 0.f) + log1pf(expf(-fabsf(x)));
    float kp = fmaxf(sp, 1e-6f);
    kap_s[tid] = kp;
    float logI;
    if (kp < 1e-3f)
      logI = 63.f * logf(kp * 0.5f + 1e-12f) - GAMMALN64;
    else
      logI = kp - 0.5f * logf(6.283185307179586f * kp + 1e-12f);
    logC_s[tid] = -63.f * logf(kp + 1e-12f) - 64.f * LOG2PI - logI;
  }
  __syncthreads();

  // block 0 publishes muhat + per-class consts for k_final
  if (b == 0) {
    for (int idx = tid; idx < KC * DD; idx += 512)
      ws[OFF_MUHAT + idx] = mu_t[idx & 127][idx >> 7];
    if (tid < KC) {
      float kp = kap_s[tid];
      float kc = fmaxf(kp, 1e-8f);
      float Aav = (kc > 50.f) ? (1.f - 127.f / (2.f * kc)) : (kc * (1.f / 128.f));
      ws[OFF_KAP + tid]  = kp;
      ws[OFF_LOGC + tid] = logC_s[tid];
      ws[OFF_AA + tid]   = Aav;
    }
  }

  // worklist: rows in our window with label == c
  const int base = sub * 1024;
  for (int t = tid; t < 1024; t += 512) {
    if (lab[base + t] == c) {
      int p = atomicAdd(&wl_cnt, 1);   // LDS atomic, tiny
      wl[p] = base + t;
    }
  }
  __syncthreads();
  const int m = wl_cnt;

  float accP = 0.f, s0 = 0.f, s1 = 0.f;
  const float2* feat2 = (const float2*)feat;
  for (int e = w; e < m; e += 8) {
    int n = wl[e];
    float2 f2 = feat2[n * 64 + l];                 // lane l holds dims 2l, 2l+1
    float ss = wave_sum(f2.x * f2.x + f2.y * f2.y);
    float inv = 1.f / fmaxf(sqrtf(ss), 1e-12f);
    float x0 = f2.x * inv, x1 = f2.y * inv;
    s0 += x0; s1 += x1;
    *(float2*)&f_s[w][2 * l] = make_float2(x0, x1); // per-wave buffer, no barrier
    __builtin_amdgcn_wave_barrier();                // pin order: write before reads
    float acc0 = 0.f, acc1 = 0.f;
    #pragma unroll
    for (int d = 0; d < DD; d += 4) {
      float4 fb = *(const float4*)&f_s[w][d];       // broadcast read
      acc0 += fb.x * mu_t[d][l]     + fb.z * mu_t[d + 2][l];
      acc1 += fb.y * mu_t[d + 1][l] + fb.w * mu_t[d + 3][l];
    }
    float Lj = logC_s[l] + kap_s[l] * (acc0 + acc1);
    float a = __shfl(Lj, c, 64);                    // L[n, c]
    float mm = fmaxf(a, Lj);
    accP += a + LN2 - (mm + log1pf(expf(-fabsf(a - Lj))));
  }

  // cross-wave reduce, plain stores (no global atomics)
  redP[w][l] = accP;
  redS[w][2 * l] = s0;
  redS[w][2 * l + 1] = s1;
  __syncthreads();
  if (tid < KC) {
    float v = 0.f;
    #pragma unroll
    for (int q = 0; q < 8; ++q) v += redP[q][tid];
    ws[OFF_PP + (unsigned)b * KC + tid] = v;
  }
  if (tid < DD) {
    float v = 0.f;
    #pragma unroll
    for (int q = 0; q < 8; ++q) v += redS[q][tid];
    ws[OFF_SUMSP + (unsigned)b * DD + tid] = v;
  }
  if (tid == 0) ws[OFF_CNTP + b] = (float)m;
}

// Kernel B: block i, one wave; lane j handles pair (i,j).
__global__ __launch_bounds__(64) void k_final(const float* __restrict__ ws,
                                              float* __restrict__ out) {
  __shared__ __align__(16) float mu_t[DD][65];
  __shared__ __align__(16) float mi[132];
  const int j = threadIdx.x, i = blockIdx.x;

  const float4* mu4 = (const float4*)(ws + OFF_MUHAT);
  #pragma unroll
  for (int q = 0; q < 32; ++q) {
    int idx4 = q * 64 + j;
    float4 v = mu4[idx4];
    int idx = idx4 * 4;
    int r = idx >> 7, d = idx & 127;
    mu_t[d][r] = v.x; mu_t[d + 1][r] = v.y; mu_t[d + 2][r] = v.z; mu_t[d + 3][r] = v.w;
  }
  __syncthreads();

  float kap_j = ws[OFF_KAP + j], logC_j = ws[OFF_LOGC + j], Aa_j = ws[OFF_AA + j];
  float kap_i = ws[OFF_KAP + i], logC_i = ws[OFF_LOGC + i], Aa_i = ws[OFF_AA + i];

  float cnt_i = 0.f, cnt_j = 0.f;
  #pragma unroll
  for (int s = 0; s < 4; ++s) {
    cnt_i += ws[OFF_CNTP + s * 64 + i];
    cnt_j += ws[OFF_CNTP + s * 64 + j];
  }
  float cs_i = fmaxf(cnt_i, 1.f), cs_j = fmaxf(cnt_j, 1.f);

  float m0 = 0.f, m1 = 0.f;
  #pragma unroll
  for (int s = 0; s < 4; ++s) {
    m0 += ws[OFF_SUMSP + (unsigned)(s * 64 + i) * DD + j];
    m1 += ws[OFF_SUMSP + (unsigned)(s * 64 + i) * DD + 64 + j];
  }
  m0 /= cs_i; m1 /= cs_i;
  if (cnt_i == 0.f) { m0 = mu_t[j][i]; m1 = mu_t[j + 64][i]; }
  mi[j] = m0; mi[j + 64] = m1;
  __syncthreads();

  float e0 = 0.f, e1 = 0.f;
  #pragma unroll
  for (int d = 0; d < DD; d += 4) {
    float4 mb = *(const float4*)&mi[d];
    e0 += mb.x * mu_t[d][j]     + mb.z * mu_t[d + 2][j];
    e1 += mb.y * mu_t[d + 1][j] + mb.w * mu_t[d + 3][j];
  }
  float dot_j = e0 + e1;

  float diag = __shfl(dot_j, i, 64);
  float E_si = kap_i * diag;
  float wgt  = fabsf((float)(i - j));
  float diff = E_si - kap_j * dot_j;
  float hinge = (i == j) ? 0.f : fmaxf(0.f, 0.5f * wgt - diff);
  float rank_part = wave_sum(hinge) / cs_i;

  float js_v;
  if (cnt_i == 0.f || cnt_j == 0.f) {
    float md = 0.f;
    for (int d = 0; d < DD; ++d) md += mu_t[d][i] * mu_t[d][j];
    float kl_ij = logC_i - logC_j + Aa_i * (kap_i - kap_j * md);
    float kl_ji = logC_j - logC_i + Aa_j * (kap_j - kap_i * md);
    js_v = 0.5f * (kl_ij + kl_ji);
  } else {
    float Pij = 0.f, Pji = 0.f;
    #pragma unroll
    for (int s = 0; s < 4; ++s) {
      Pij += ws[OFF_PP + (unsigned)(s * 64 + i) * KC + j];
      Pji += ws[OFF_PP + (unsigned)(s * 64 + j) * KC + i];
    }
    js_v = 0.5f * (Pij / cs_i + Pji / cs_j);
  }
  float js_part = wave_sum(wgt * js_v);
  if (j == 0)
    atomicAdd(out, rank_part * (1.f / 4096.f) + js_part * (1.f / 87360.f));
}

extern "C" void kernel_launch(void* const* d_in, const int* in_sizes, int n_in,
                              void* d_out, int out_size, void* d_ws, size_t ws_size,
                              hipStream_t stream) {
  const float* feat = (const float*)d_in[0];
  const float* musp = (const float*)d_in[1];
  const float* rho  = (const float*)d_in[2];
  const int*   lab  = (const int*)d_in[3];
  float* ws  = (float*)d_ws;
  float* out = (float*)d_out;

  hipMemsetAsync(out, 0, sizeof(float), stream);
  k_classes<<<256, 512, 0, stream>>>(feat, musp, rho, lab, ws);
  k_final<<<64, 64, 0, stream>>>(ws, out);
}